// Round 13
// baseline (350.114 us; speedup 1.0000x reference)
//
#include <hip/hip_runtime.h>
#include <math.h>

// B=4, O=8, C=256, HID=128, H=W=64, STEPS=2
// v13 = v12 + objconv moved to conv_obj@(256,2): 4-row blocks (128co x 256px,
// acc[4][8]), single act [6][64][32] + 3-slot W, 1-barrier counted-vmcnt taps
// (v10-verified protocol). At (256,2): VGPR budget 256 >= ~212 need -> NO
// spill (v10's 485MB-scratch failure was the (256,3) 170-reg cap). Capacity =
// min(LDS 163840/49152=3, VGPR 2) = 2/CU x 256 = 512 = grid -> SINGLE
// co-resident wave, zero tail (v12's 1024-block objconv ran 2 full waves).
// enc/sh convs keep v11 conv_k; ro_shared/ro_obj keep LDS-staged form.
//   prep -> encconv(4 kz-partials) -> [ro_shared + enc_obj_sum] ->
//   shconv1 -> objconv1(FUSE) -> shconv2(SUMIN) -> objconv2(FUSE) -> ro_obj
// Activations fp16 chunked HWC: x[img][cc][px][ci32] (4KB DMA-able slabs).

typedef unsigned short ushort_t;
typedef _Float16 f16x8 __attribute__((ext_vector_type(8)));
typedef _Float16 f16x2 __attribute__((ext_vector_type(2)));
typedef float f32x4 __attribute__((ext_vector_type(4)));

#define GLDS(gsrc, ldst)                                                      \
    __builtin_amdgcn_global_load_lds(                                         \
        (const __attribute__((address_space(1))) unsigned int*)(gsrc),        \
        (__attribute__((address_space(3))) unsigned int*)(ldst), 16, 0, 0)

#define WAITVM0() asm volatile("s_waitcnt vmcnt(0)" ::: "memory")
#define WAITVM2() asm volatile("s_waitcnt vmcnt(2)" ::: "memory")
#define WAITLGKM0() asm volatile("s_waitcnt lgkmcnt(0)" ::: "memory")

__device__ __forceinline__ ushort_t f2h(float f) {
    _Float16 h = (_Float16)f;
    return *(ushort_t*)&h;
}
__device__ __forceinline__ float h2f(ushort_t u) {
    _Float16 h = *(_Float16*)&u;
    return (float)h;
}

// ---- merged prep: blocks <1024: feats CHW->chunked HWC; rest: weight packing
__global__ __launch_bounds__(256) void prep_all(
    const float* __restrict__ feats, const float* __restrict__ enc_w,
    const float* __restrict__ gcn_w, const float* __restrict__ ro_w,
    ushort_t* __restrict__ featsT, ushort_t* __restrict__ WencF,
    ushort_t* __restrict__ WgcnS, ushort_t* __restrict__ WgcnD,
    ushort_t* __restrict__ WroQ, ushort_t* __restrict__ WroS)
{
    __shared__ float tile[64][65];
    int bid = blockIdx.x, t = threadIdx.x;
    if (bid < 1024) {                 // feats transform: pt|ct|img
        int pt = bid & 63, ct = (bid >> 6) & 3, img = bid >> 8;
        int px_l = t & 63;
        const float* src = feats + ((size_t)img * 256 + ct * 64) * 4096 + pt * 64;
#pragma unroll
        for (int j = 0; j < 16; ++j) {
            int ci_l = (t >> 6) + j * 4;
            tile[px_l][ci_l] = src[(size_t)ci_l * 4096 + px_l];
        }
        __syncthreads();
        int px = t >> 2;
#pragma unroll
        for (int j = 0; j < 2; ++j) {
            int c8 = ((t & 3) + j * 4) * 8;
            uint4 v; ushort_t* pv = (ushort_t*)&v;
#pragma unroll
            for (int k = 0; k < 8; ++k) pv[k] = f2h(tile[px][c8 + k]);
            int cc = ct * 2 + (c8 >> 5);
            *(uint4*)(featsT + ((size_t)img * 8 + cc) * 131072 +
                      (size_t)(pt * 64 + px) * 32 + (c8 & 31)) = v;
        }
        return;
    }
    int i = (bid - 1024) * 256 + t;
    if (i < 294912) {                 // WencF[t][cc8][co128][ci32]
        int ci32 = i & 31, co = (i >> 5) & 127, tc = i >> 12;
        int tt = tc >> 3, cc = tc & 7, ci = cc * 32 + ci32;
        WencF[i] = f2h(enc_w[(co * 257 + ci) * 9 + tt]);
    } else if (i < 442368) {          // WgcnS[t][cc4][co128][ci32]
        int j = i - 294912;
        int ci32 = j & 31, co = (j >> 5) & 127, tc = j >> 12;
        int tt = tc >> 2, cc = tc & 3, ci = cc * 32 + ci32;
        WgcnS[j] = f2h(gcn_w[(co * 256 + 128 + ci) * 9 + tt]);
    } else if (i < 589824) {          // WgcnD = W1 - W2
        int j = i - 442368;
        int ci32 = j & 31, co = (j >> 5) & 127, tc = j >> 12;
        int tt = tc >> 2, cc = tc & 3, ci = cc * 32 + ci32;
        WgcnD[j] = f2h(gcn_w[(co * 256 + ci) * 9 + tt] -
                       gcn_w[(co * 256 + 128 + ci) * 9 + tt]);
    } else if (i < 592128) {          // WroQ[8cc][4q][9t][8k]
        int j = i - 589824;
        int k = j & 7, r = j >> 3;
        int tt = r % 9, cq = r / 9, q = cq & 3, cc = cq >> 2;
        WroQ[j] = f2h(ro_w[(cc * 32 + q * 8 + k) * 9 + tt]);
    } else if (i < 593280) {          // WroS[4cc][4q][9t][8k]
        int j = i - 592128;
        int k = j & 7, r = j >> 3;
        int tt = r % 9, cq = r / 9, q = cq & 3, cc = cq >> 2;
        WroS[j] = f2h(ro_w[(256 + cc * 32 + q * 8 + k) * 9 + tt]);
    }
}

// ---- conv v11 (proven): enc/sh convs. grid (32 rowpairs, nimg, kz). Block:
// 128co x 128px, 4 waves (cg,pg); wave 64co x 64px. Single halo act
// [4][66][32]; 3-slot W rotation; 1 barrier/steady tap; counted vmcnt(2);
// vmcnt(0) only at the final tap.
// Swizzle: LDS(col,s') = global(col, s'^g(col)), g=(col>>1)&3.
// FUSE:  epilogue = relu(raw + sum4(addp partials) + bias) (gcn object conv).
// SUMIN: act staging sums 8 objects (img = batch; object stride ncc_img*131072).
template<int NCCBLK, bool FUSE, bool SUMIN>
__global__ __launch_bounds__(256, 3) void conv_k(
    const ushort_t* __restrict__ x, const ushort_t* __restrict__ W,
    ushort_t* __restrict__ out,
    const ushort_t* __restrict__ addp, const float* __restrict__ bias,
    int ncc_img)
{
    __shared__ ushort_t raw[20736];           // 41472 B -> 3 blocks/CU
    ushort_t* xs = raw;                       // [4 rows][66 cols][32ci] single
    ushort_t* wlds = raw + 8448;              // 3 x [128 co][32ci]
    ushort_t* eb16 = raw;                     // epilogue overlay [64][136]

    const int rp = blockIdx.x, img = blockIdx.y, kz = blockIdx.z;
    const int row0 = rp * 2;
    const int cc0 = kz * NCCBLK;
    const int nchunk = 9 * NCCBLK;
    const int tid = threadIdx.x;
    const int w = tid >> 6, lane = tid & 63, lq = lane >> 4, lr = lane & 15;
    const int cg = w >> 1, pg = w & 1;

    const size_t objstride = (size_t)ncc_img * 131072;
    const ushort_t* xb = SUMIN ? x + (size_t)img * 8 * objstride
                               : x + (size_t)img * objstride;
    // A-read base with slot swizzle: co = cg*64+lr (+16 per frag, g-invariant)
    const int aoff0 = (cg * 64 + lr) * 32 + (lq ^ ((lr >> 1) & 3)) * 8;

    // zero halo columns (0 and 65) of the act buffer, once (all slots -> inv)
    if (tid < 32) {
        int r = tid >> 3, c = (tid >> 2) & 1, s = tid & 3;
        *(uint4*)(xs + r * 2112 + (c ? 65 : 0) * 32 + s * 8) =
            make_uint4(0, 0, 0, 0);
    }

    f32x4 acc[4][4];
#pragma unroll
    for (int a = 0; a < 4; ++a)
#pragma unroll
        for (int p = 0; p < 4; ++p) acc[a][p] = (f32x4){0.f, 0.f, 0.f, 0.f};

    const int gy = row0 - 1 + w;
    const bool row_ok = (unsigned)gy < 64u;
#define STAGE_ACT(cc_)                                                          \
    {                                                                           \
        ushort_t* dstrow = xs + w * 2112;                                       \
        if (row_ok) {                                                           \
            const ushort_t* src = xb + (size_t)(cc_) * 131072 + (size_t)gy * 2048; \
            if constexpr (SUMIN) {                                              \
                _Pragma("unroll")                                               \
                for (int u_ = 0; u_ < 4; ++u_) {                                \
                    f16x8 a_ = {0, 0, 0, 0, 0, 0, 0, 0};                        \
                    _Pragma("unroll")                                           \
                    for (int o_ = 0; o_ < 8; ++o_)                              \
                        a_ = a_ + *(const f16x8*)(src + (size_t)o_ * objstride + \
                                                  u_ * 512 + lane * 8);         \
                    int colp_ = 1 + u_ * 16 + (lane >> 2);                      \
                    int ssw_ = (lane & 3) ^ ((colp_ >> 1) & 3);                 \
                    *(f16x8*)(dstrow + colp_ * 32 + ssw_ * 8) = a_;             \
                }                                                               \
            } else {                                                            \
                _Pragma("unroll")                                               \
                for (int u_ = 0; u_ < 4; ++u_) {                                \
                    int colp_ = 1 + u_ * 16 + (lane >> 2);                      \
                    int ssw_ = (lane & 3) ^ ((colp_ >> 1) & 3);                 \
                    GLDS(src + (size_t)(colp_ - 1) * 32 + ssw_ * 8,             \
                         dstrow + 32 + u_ * 512);                               \
                }                                                               \
            }                                                                   \
        } else {                                                                \
            _Pragma("unroll")                                                   \
            for (int u_ = 0; u_ < 4; ++u_)                                      \
                *(uint4*)(dstrow + 32 + u_ * 512 + lane * 8) =                  \
                    make_uint4(0, 0, 0, 0);                                     \
        }                                                                       \
    }
#define STAGE_W(t_, cc_, slot_)                                                 \
    {                                                                           \
        const ushort_t* src = W + ((size_t)((t_) * ncc_img + (cc_)) * 4096);    \
        ushort_t* dst = wlds + (slot_) * 4096;                                  \
        _Pragma("unroll")                                                       \
        for (int j_ = 0; j_ < 2; ++j_) {                                        \
            int co_ = (w * 2 + j_) * 16 + (lane >> 2);                          \
            int ssw_ = (lane & 3) ^ ((co_ >> 1) & 3);                           \
            GLDS(src + co_ * 32 + ssw_ * 8, dst + (w * 2 + j_) * 512);          \
        }                                                                       \
    }

    STAGE_ACT(cc0);
    STAGE_W(0, cc0, 0);
    STAGE_W(1, cc0, 1);
    WAITLGKM0();                 // publish halo zeros / SUMIN ds_writes

#pragma unroll
    for (int ccl = 0; ccl < NCCBLK; ++ccl) {
        const int cc = cc0 + ccl;
#pragma unroll
        for (int t = 0; t < 9; ++t) {
            const int kc = ccl * 9 + t;
            // entry: W[kc] (staged kc-2) landed; W[kc+1] stays in flight
            if (kc == nchunk - 1) { WAITVM0(); } else { WAITVM2(); }
            __builtin_amdgcn_s_barrier();

            if (t == 0 && ccl > 0) {
                // act[cc-1] reads were MFMA-consumed before the entry barrier
                STAGE_ACT(cc);
                if (kc + 2 < nchunk)
                    STAGE_W((kc + 2) % 9, cc0 + (kc + 2) / 9, (kc + 2) % 3);
                WAITVM2();       // act landed (leaves W[kc+2] in flight)
                WAITLGKM0();     // !row_ok zero ds_writes published
                __builtin_amdgcn_s_barrier();
            } else if (kc + 2 < nchunk) {
                // slot (kc+2)%3 held W[kc-1]: reads consumed at tap kc-1
                STAGE_W((kc + 2) % 9, cc0 + (kc + 2) / 9, (kc + 2) % 3);
            }

            const int dy = t / 3, dx = t - 3 * dy;
            const ushort_t* wl = wlds + (kc % 3) * 4096 + aoff0;
            const int colb = dx + lr;
            const int swb = lq ^ ((colb >> 1) & 3);
            const ushort_t* xl = xs + (pg + dy) * 2112 + colb * 32 + swb * 8;
            f16x8 A0 = *(const f16x8*)(wl);
            f16x8 A1 = *(const f16x8*)(wl + 512);
            f16x8 A2 = *(const f16x8*)(wl + 1024);
            f16x8 A3 = *(const f16x8*)(wl + 1536);
            f16x8 B0 = *(const f16x8*)(xl);
            f16x8 B1 = *(const f16x8*)(xl + 512);
            f16x8 B2 = *(const f16x8*)(xl + 1024);
            f16x8 B3 = *(const f16x8*)(xl + 1536);

            __builtin_amdgcn_s_setprio(1);
            acc[0][0] = __builtin_amdgcn_mfma_f32_16x16x32_f16(A0, B0, acc[0][0], 0, 0, 0);
            acc[1][0] = __builtin_amdgcn_mfma_f32_16x16x32_f16(A1, B0, acc[1][0], 0, 0, 0);
            acc[2][0] = __builtin_amdgcn_mfma_f32_16x16x32_f16(A2, B0, acc[2][0], 0, 0, 0);
            acc[3][0] = __builtin_amdgcn_mfma_f32_16x16x32_f16(A3, B0, acc[3][0], 0, 0, 0);
            acc[0][1] = __builtin_amdgcn_mfma_f32_16x16x32_f16(A0, B1, acc[0][1], 0, 0, 0);
            acc[1][1] = __builtin_amdgcn_mfma_f32_16x16x32_f16(A1, B1, acc[1][1], 0, 0, 0);
            acc[2][1] = __builtin_amdgcn_mfma_f32_16x16x32_f16(A2, B1, acc[2][1], 0, 0, 0);
            acc[3][1] = __builtin_amdgcn_mfma_f32_16x16x32_f16(A3, B1, acc[3][1], 0, 0, 0);
            acc[0][2] = __builtin_amdgcn_mfma_f32_16x16x32_f16(A0, B2, acc[0][2], 0, 0, 0);
            acc[1][2] = __builtin_amdgcn_mfma_f32_16x16x32_f16(A1, B2, acc[1][2], 0, 0, 0);
            acc[2][2] = __builtin_amdgcn_mfma_f32_16x16x32_f16(A2, B2, acc[2][2], 0, 0, 0);
            acc[3][2] = __builtin_amdgcn_mfma_f32_16x16x32_f16(A3, B2, acc[3][2], 0, 0, 0);
            acc[0][3] = __builtin_amdgcn_mfma_f32_16x16x32_f16(A0, B3, acc[0][3], 0, 0, 0);
            acc[1][3] = __builtin_amdgcn_mfma_f32_16x16x32_f16(A1, B3, acc[1][3], 0, 0, 0);
            acc[2][3] = __builtin_amdgcn_mfma_f32_16x16x32_f16(A2, B3, acc[2][3], 0, 0, 0);
            acc[3][3] = __builtin_amdgcn_mfma_f32_16x16x32_f16(A3, B3, acc[3][3], 0, 0, 0);
            __builtin_amdgcn_s_setprio(0);
        }
    }

    // ---- epilogue via LDS transpose, fp16 chunked out
    ushort_t* obase = out + (size_t)(kz * gridDim.y + img) * 524288;
    const int b4 = img >> 3;                  // batch (FUSE only)
#pragma unroll
    for (int r = 0; r < 2; ++r) {
        __syncthreads();
        if (pg == r) {
#pragma unroll
            for (int cf = 0; cf < 4; ++cf)
#pragma unroll
                for (int pf = 0; pf < 4; ++pf) {
                    int px = pf * 16 + lr;
                    int co_l = cg * 64 + cf * 16 + lq * 4;
                    ushort_t pk[4];
#pragma unroll
                    for (int j = 0; j < 4; ++j) pk[j] = f2h(acc[cf][pf][j]);
                    *(uint2*)(eb16 + px * 136 + co_l) = *(uint2*)pk;
                }
        }
        __syncthreads();
#pragma unroll
        for (int k2 = 0; k2 < 4; ++k2) {
            int i = tid + k2 * 256;
            int px = i >> 4, c16 = i & 15;
            int pxg = (row0 + r) * 64 + px;
            size_t coff = (size_t)(c16 >> 2) * 131072 + (size_t)pxg * 32 + (c16 & 3) * 8;
            uint4 v = *(uint4*)(eb16 + px * 136 + c16 * 8);
            if constexpr (FUSE) {
                const ushort_t* vp = (const ushort_t*)&v;
                float vv[8];
#pragma unroll
                for (int k = 0; k < 8; ++k) vv[k] = h2f(vp[k]) + bias[c16 * 8 + k];
#pragma unroll
                for (int p = 0; p < 4; ++p) {
                    uint4 av = *(const uint4*)(addp + (size_t)(p * 4 + b4) * 524288 + coff);
                    const ushort_t* ap = (const ushort_t*)&av;
#pragma unroll
                    for (int k = 0; k < 8; ++k) vv[k] += h2f(ap[k]);
                }
                uint4 sv; ushort_t* sp = (ushort_t*)&sv;
#pragma unroll
                for (int k = 0; k < 8; ++k) sp[k] = f2h(fmaxf(vv[k], 0.f));
                *(uint4*)(obase + coff) = sv;
            } else {
                *(uint4*)(obase + coff) = v;
            }
        }
    }
#undef STAGE_ACT
#undef STAGE_W
}

// ---- conv_obj: objconv only (NCCBLK=4, FUSE, ncc_img=4). 4-row blocks
// (128co x 256px), 4 waves of 64co x 128px, acc[4][8]. Single act buffer
// [6][64][32] (staged per cc), 3-slot W rotation (W[kc] in slot kc%3, staged
// at kc-2). Steady tap: vmcnt(2); s_barrier; stage W[kc+2]; ds_read A/B
// (B col-clamped at image edge); 32 MFMA. cc boundary: stage act + W, mid
// vmcnt(2)+lgkm0+barrier. (256,2): VGPR budget 256 (acc 128 + ~84 arch fits,
// NO spill — v10's (256,3) spilled). LDS 49152; capacity 2/CU x 256 = 512 =
// grid (16,32) -> single co-resident wave, ZERO TAIL.
__global__ __launch_bounds__(256, 2) void conv_obj(
    const ushort_t* __restrict__ x, const ushort_t* __restrict__ W,
    ushort_t* __restrict__ out, const ushort_t* __restrict__ addp,
    const float* __restrict__ bias)
{
    __shared__ ushort_t raw[24576];           // 49152 B
    ushort_t* xs = raw;                       // [6][64][32] single act
    ushort_t* wlds = raw + 12288;             // 3 x [128 co][32ci]
    ushort_t* eb16 = raw;                     // epilogue overlay [64][136]

    const int rq = blockIdx.x, img = blockIdx.y;
    const int row0 = rq * 4;
    const int tid = threadIdx.x;
    const int w = tid >> 6, lane = tid & 63, lq = lane >> 4, lr = lane & 15;
    const int cg = w >> 1, pg = w & 1;

    const ushort_t* xb = x + (size_t)img * 524288;   // ncc_img = 4
    const int aoff0 = (cg * 64 + lr) * 32 + (lq ^ ((lr >> 1) & 3)) * 8;

    f32x4 acc[4][8];
#pragma unroll
    for (int a = 0; a < 4; ++a)
#pragma unroll
        for (int p = 0; p < 8; ++p) acc[a][p] = (f32x4){0.f, 0.f, 0.f, 0.f};

#define STAGE_ACT4(cc_)                                                         \
    {                                                                           \
        const ushort_t* srcb = xb + (size_t)(cc_) * 131072;                     \
        _Pragma("unroll")                                                       \
        for (int j_ = 0; j_ < 6; ++j_) {                                        \
            int idx_ = w * 6 + j_, rl_ = idx_ >> 2, q_ = idx_ & 3;              \
            int gy_ = row0 - 1 + rl_;                                           \
            ushort_t* dst_ = xs + rl_ * 2048 + q_ * 512;                        \
            if ((unsigned)gy_ < 64u) {                                          \
                int col_ = q_ * 16 + (lane >> 2);                               \
                int ss_ = (lane & 3) ^ ((col_ >> 1) & 3);                       \
                GLDS(srcb + (size_t)gy_ * 2048 + col_ * 32 + ss_ * 8, dst_);    \
            } else {                                                            \
                *(uint4*)(dst_ + lane * 8) = make_uint4(0, 0, 0, 0);            \
            }                                                                   \
        }                                                                       \
    }
#define STAGE_W3(t_, cc_, buf_)                                                 \
    {                                                                           \
        const ushort_t* src = W + ((size_t)((t_) * 4 + (cc_)) * 4096);          \
        ushort_t* dst = wlds + (buf_) * 4096;                                   \
        _Pragma("unroll")                                                       \
        for (int j_ = 0; j_ < 2; ++j_) {                                        \
            int co_ = (w * 2 + j_) * 16 + (lane >> 2);                          \
            int ssw_ = (lane & 3) ^ ((co_ >> 1) & 3);                           \
            GLDS(src + co_ * 32 + ssw_ * 8, dst + (w * 2 + j_) * 512);          \
        }                                                                       \
    }

    STAGE_ACT4(0);
    STAGE_W3(0, 0, 0);
    STAGE_W3(1, 0, 1);

#pragma unroll
    for (int ccl = 0; ccl < 4; ++ccl) {
#pragma unroll
        for (int t = 0; t < 9; ++t) {
            const int kc = ccl * 9 + t;
            if (t == 0) {
                if (ccl == 0) {
                    // prologue: act + W[0] landed (leaves W[1] in flight)
                    WAITVM2(); WAITLGKM0();
                    __builtin_amdgcn_s_barrier();
                } else {
                    WAITVM2();                    // W[kc] landed
                    __builtin_amdgcn_s_barrier(); // act[cc-1] reads consumed
                    STAGE_ACT4(ccl);
                    STAGE_W3((kc + 2) % 9, (kc + 2) / 9, (kc + 2) % 3);
                    WAITVM2();                    // act landed (leaves W[kc+2])
                    WAITLGKM0();                  // zero-row ds_writes published
                    __builtin_amdgcn_s_barrier();
                }
            } else {
                if (kc == 35) { WAITVM0(); } else { WAITVM2(); }
                __builtin_amdgcn_s_barrier();
            }
            // steady-stage: slot (kc+2)%3 = slot of W[kc-1], whose reads were
            // consumed by tap kc-1's MFMAs before this tap's entry barrier.
            if ((t != 0 || ccl == 0) && kc + 2 < 36)
                STAGE_W3((kc + 2) % 9, (kc + 2) / 9, (kc + 2) % 3);

            const int dy = t / 3, dx = t - 3 * dy;
            const ushort_t* wl = wlds + (kc % 3) * 4096 + aoff0;
            f16x8 A0 = *(const f16x8*)(wl);
            f16x8 A1 = *(const f16x8*)(wl + 512);
            f16x8 A2 = *(const f16x8*)(wl + 1024);
            f16x8 A3 = *(const f16x8*)(wl + 1536);

            __builtin_amdgcn_s_setprio(1);
#pragma unroll
            for (int pf = 0; pf < 8; ++pf) {
                const int rl = 2 * pg + (pf >> 2) + dy;      // act row 0..5
                const int c = (pf & 3) * 16 + lr + dx - 1;   // global col
                const int c2 = c < 0 ? 0 : (c > 63 ? 63 : c);
                f16x8 Bf = *(const f16x8*)(xs + rl * 2048 + c2 * 32 +
                                           (lq ^ ((c2 >> 1) & 3)) * 8);
                if (c != c2) Bf = (f16x8){0, 0, 0, 0, 0, 0, 0, 0};
                acc[0][pf] = __builtin_amdgcn_mfma_f32_16x16x32_f16(A0, Bf, acc[0][pf], 0, 0, 0);
                acc[1][pf] = __builtin_amdgcn_mfma_f32_16x16x32_f16(A1, Bf, acc[1][pf], 0, 0, 0);
                acc[2][pf] = __builtin_amdgcn_mfma_f32_16x16x32_f16(A2, Bf, acc[2][pf], 0, 0, 0);
                acc[3][pf] = __builtin_amdgcn_mfma_f32_16x16x32_f16(A3, Bf, acc[3][pf], 0, 0, 0);
            }
            __builtin_amdgcn_s_setprio(0);
        }
    }

    // ---- epilogue: 4 row-phases via LDS transpose, FUSE
    ushort_t* obase = out + (size_t)img * 524288;
    const int b4 = img >> 3;
#pragma unroll
    for (int r = 0; r < 4; ++r) {
        __syncthreads();
        if (pg == (r >> 1)) {
            const int pb = (r & 1) * 4;
#pragma unroll
            for (int cf = 0; cf < 4; ++cf)
#pragma unroll
                for (int pf2 = 0; pf2 < 4; ++pf2) {
                    int px = pf2 * 16 + lr;
                    int co_l = cg * 64 + cf * 16 + lq * 4;
                    ushort_t pk[4];
#pragma unroll
                    for (int j = 0; j < 4; ++j) pk[j] = f2h(acc[cf][pb + pf2][j]);
                    *(uint2*)(eb16 + px * 136 + co_l) = *(uint2*)pk;
                }
        }
        __syncthreads();
#pragma unroll
        for (int k2 = 0; k2 < 4; ++k2) {
            int i = tid + k2 * 256;
            int px = i >> 4, c16 = i & 15;
            int pxg = (row0 + r) * 64 + px;
            size_t coff = (size_t)(c16 >> 2) * 131072 + (size_t)pxg * 32 + (c16 & 3) * 8;
            uint4 v = *(uint4*)(eb16 + px * 136 + c16 * 8);
            const ushort_t* vp = (const ushort_t*)&v;
            float vv[8];
#pragma unroll
            for (int k = 0; k < 8; ++k) vv[k] = h2f(vp[k]) + bias[c16 * 8 + k];
#pragma unroll
            for (int p = 0; p < 4; ++p) {
                uint4 av = *(const uint4*)(addp + (size_t)(p * 4 + b4) * 524288 + coff);
                const ushort_t* ap = (const ushort_t*)&av;
#pragma unroll
                for (int k = 0; k < 8; ++k) vv[k] += h2f(ap[k]);
            }
            uint4 sv; ushort_t* sp = (ushort_t*)&sv;
#pragma unroll
            for (int k = 0; k < 8; ++k) sp[k] = f2h(fmaxf(vv[k], 0.f));
            *(uint4*)(obase + coff) = sv;
        }
    }
#undef STAGE_ACT4
#undef STAGE_W3
}

// ---- merged: bid<64: ro_shared v2 (LDS-staged, one block per (rq,b));
//              bid>=64: encoder per-object + object-sum (1024 blocks)
__global__ __launch_bounds__(256) void enc_obj_ro(
    const float* __restrict__ masks, const float* __restrict__ enc_w,
    const float* __restrict__ enc_b, const ushort_t* __restrict__ U1p,
    const ushort_t* __restrict__ featsT, const ushort_t* __restrict__ WroQ,
    ushort_t* __restrict__ S, ushort_t* __restrict__ USum,
    float* __restrict__ YR)
{
    __shared__ ushort_t sl[12288 + 2304];     // ro: [6][64][32] acts + WroQ
    ushort_t* wl = sl + 12288;
    int bid = blockIdx.x, tid = threadIdx.x;
    if (bid < 64) {
        // ---- ro_shared v2: bid = rq*4 + b; 4 output rows, 8 cc of featsT
        const int rq = bid >> 2, b = bid & 3;
        const int lane = tid & 63;
        const int yl = tid >> 6, x = tid & 63;
#pragma unroll
        for (int k = 0; k < 2; ++k) {         // WroQ: 2304 us = 288 uint4
            int idx = tid + k * 256;
            if (idx < 288)
                *(uint4*)(wl + idx * 8) = *(const uint4*)(WroQ + idx * 8);
        }
        float acc = 0.f;
#pragma unroll
        for (int cc = 0; cc < 8; ++cc) {
            __syncthreads();                  // prev-cc reads done (+W on cc=0)
            const ushort_t* fb = featsT + (size_t)(b * 8 + cc) * 131072;
#pragma unroll
            for (int k = 0; k < 6; ++k) {
                int c = (tid >> 6) * 6 + k;   // chunk 0..23
                int j = c >> 2, qd = c & 3;
                int gyr = rq * 4 - 1 + j;
                ushort_t* dst = sl + j * 2048 + qd * 512;   // wave-uniform
                if ((unsigned)gyr < 64u) {
                    int colq = qd * 16 + (lane >> 2);
                    GLDS(fb + (size_t)gyr * 2048 + colq * 32 +
                             ((lane & 3) ^ ((colq >> 1) & 3)) * 8,
                         dst);
                } else {
                    *(uint4*)(dst + lane * 8) = make_uint4(0, 0, 0, 0);
                }
            }
            __syncthreads();                  // drains vmcnt (GLDS) + lgkm
#pragma unroll
            for (int dy = 0; dy < 3; ++dy) {
                const ushort_t* rowp = sl + (yl + dy) * 2048;
#pragma unroll
                for (int dx = 0; dx < 3; ++dx) {
                    int gx = x + dx - 1;
                    if ((unsigned)gx >= 64u) continue;
                    const int tap = dy * 3 + dx;
#pragma unroll
                    for (int q = 0; q < 4; ++q) {
                        f16x8 sv = *(const f16x8*)(rowp + gx * 32 +
                                                   (q ^ ((gx >> 1) & 3)) * 8);
                        f16x8 wv = *(const f16x8*)(wl + ((cc * 4 + q) * 9 + tap) * 8);
                        f16x2 s0 = {sv[0], sv[1]}, s1 = {sv[2], sv[3]};
                        f16x2 s2 = {sv[4], sv[5]}, s3 = {sv[6], sv[7]};
                        f16x2 w0 = {wv[0], wv[1]}, w1 = {wv[2], wv[3]};
                        f16x2 w2 = {wv[4], wv[5]}, w3 = {wv[6], wv[7]};
                        acc = __builtin_amdgcn_fdot2(s0, w0, acc, false);
                        acc = __builtin_amdgcn_fdot2(s1, w1, acc, false);
                        acc = __builtin_amdgcn_fdot2(s2, w2, acc, false);
                        acc = __builtin_amdgcn_fdot2(s3, w3, acc, false);
                    }
                }
            }
        }
        YR[b * 4096 + (rq * 4 + yl) * 64 + x] = acc;
        return;
    }
    // ---- enc_obj_sum: i = b(2)|cc(2)|px(12)|s(2)
    int i = (bid - 64) * 256 + tid;
    int s = i & 3, px = (i >> 2) & 4095, cc = (i >> 14) & 3, b = i >> 16;
    int co = cc * 32 + s * 8;
    int y = px >> 6, xx = px & 63;
    size_t coff = (size_t)cc * 131072 + (size_t)px * 32 + s * 8;
    float base[8];
#pragma unroll
    for (int k = 0; k < 8; ++k) base[k] = enc_b[co + k];
#pragma unroll
    for (int p = 0; p < 4; ++p) {
        uint4 v = *(const uint4*)(U1p + (size_t)(p * 4 + b) * 524288 + coff);
        const ushort_t* vp = (const ushort_t*)&v;
#pragma unroll
        for (int k = 0; k < 8; ++k) base[k] += h2f(vp[k]);
    }
    float wm[8][9];
#pragma unroll
    for (int k = 0; k < 8; ++k) {
        const float* wp = enc_w + (size_t)((co + k) * 257 + 256) * 9;
#pragma unroll
        for (int t = 0; t < 9; ++t) wm[k][t] = wp[t];
    }
    float sacc[8] = {0, 0, 0, 0, 0, 0, 0, 0};
#pragma unroll
    for (int o = 0; o < 8; ++o) {
        const float* m = masks + (size_t)(b * 8 + o) * 4096;
        float mt[9];
#pragma unroll
        for (int dy = 0; dy < 3; ++dy)
#pragma unroll
            for (int dx = 0; dx < 3; ++dx) {
                int gy_ = y + dy - 1, gx = xx + dx - 1;
                mt[dy * 3 + dx] =
                    ((unsigned)gy_ < 64u && (unsigned)gx < 64u) ? m[gy_ * 64 + gx] : 0.f;
            }
        uint4 sv; ushort_t* sp = (ushort_t*)&sv;
#pragma unroll
        for (int k = 0; k < 8; ++k) {
            float acc = base[k];
#pragma unroll
            for (int t = 0; t < 9; ++t) acc = fmaf(mt[t], wm[k][t], acc);
            acc = fmaxf(acc, 0.f);
            sacc[k] += acc;
            sp[k] = f2h(acc);
        }
        *(uint4*)(S + (size_t)(b * 8 + o) * 524288 + coff) = sv;
    }
    uint4 sv; ushort_t* sp = (ushort_t*)&sv;
#pragma unroll
    for (int k = 0; k < 8; ++k) sp[k] = f2h(sacc[k]);
    *(uint4*)(USum + (size_t)b * 524288 + coff) = sv;
}

// ---- readout per-object v2: LDS-staged. grid (16 rowquads, 32 n).
__global__ __launch_bounds__(256) void ro_obj(
    const ushort_t* __restrict__ S, const ushort_t* __restrict__ WroS,
    const float* __restrict__ ro_b, const float* __restrict__ YR,
    float* __restrict__ out)
{
    __shared__ ushort_t sl[12288 + 1152];     // [6][64][32] acts + weights
    ushort_t* wl = sl + 12288;
    const int rq = blockIdx.x;                // 0..15 (4 rows each)
    const int n  = blockIdx.y;                // 0..31
    const int b  = n >> 3;
    const int tid = threadIdx.x;
    const int lane = tid & 63;
    const int yl = tid >> 6, x = tid & 63;    // output row-in-block, col

    if (tid < 144)                            // weights: 1152 us = 144 uint4
        *(uint4*)(wl + tid * 8) = *(const uint4*)(WroS + tid * 8);

    float acc = 0.f;
#pragma unroll
    for (int cc = 0; cc < 4; ++cc) {
        __syncthreads();                      // prev-cc reads done (+W on cc=0)
        const ushort_t* sb = S + ((size_t)n * 4 + cc) * 131072;
#pragma unroll
        for (int k = 0; k < 6; ++k) {
            int c = (tid >> 6) * 6 + k;       // chunk 0..23
            int j = c >> 2, qd = c & 3;
            int gyr = rq * 4 - 1 + j;
            ushort_t* dst = sl + j * 2048 + qd * 512;   // wave-uniform
            if ((unsigned)gyr < 64u) {
                int colq = qd * 16 + (lane >> 2);
                GLDS(sb + (size_t)gyr * 2048 + colq * 32 +
                         ((lane & 3) ^ ((colq >> 1) & 3)) * 8,
                     dst);
            } else {
                *(uint4*)(dst + lane * 8) = make_uint4(0, 0, 0, 0);
            }
        }
        __syncthreads();                      // drains vmcnt (GLDS) + lgkm
#pragma unroll
        for (int dy = 0; dy < 3; ++dy) {
            const ushort_t* rowp = sl + (yl + dy) * 2048;
#pragma unroll
            for (int dx = 0; dx < 3; ++dx) {
                int gx = x + dx - 1;
                if ((unsigned)gx >= 64u) continue;
                const int tap = dy * 3 + dx;
#pragma unroll
                for (int q = 0; q < 4; ++q) {
                    f16x8 sv = *(const f16x8*)(rowp + gx * 32 +
                                               (q ^ ((gx >> 1) & 3)) * 8);
                    f16x8 wv = *(const f16x8*)(wl + ((cc * 4 + q) * 9 + tap) * 8);
                    f16x2 s0 = {sv[0], sv[1]}, s1 = {sv[2], sv[3]};
                    f16x2 s2 = {sv[4], sv[5]}, s3 = {sv[6], sv[7]};
                    f16x2 w0 = {wv[0], wv[1]}, w1 = {wv[2], wv[3]};
                    f16x2 w2 = {wv[4], wv[5]}, w3 = {wv[6], wv[7]};
                    acc = __builtin_amdgcn_fdot2(s0, w0, acc, false);
                    acc = __builtin_amdgcn_fdot2(s1, w1, acc, false);
                    acc = __builtin_amdgcn_fdot2(s2, w2, acc, false);
                    acc = __builtin_amdgcn_fdot2(s3, w3, acc, false);
                }
            }
        }
    }
    int pxg = (rq * 4 + yl) * 64 + x;
    float v = acc + YR[b * 4096 + pxg] + ro_b[0];
    out[(size_t)n * 4096 + pxg] = 1.f / (1.f + __expf(-v));
}

extern "C" void kernel_launch(void* const* d_in, const int* in_sizes, int n_in,
                              void* d_out, int out_size, void* d_ws, size_t ws_size,
                              hipStream_t stream)
{
    const float* feats = (const float*)d_in[0];   // [4,256,64,64]
    const float* masks = (const float*)d_in[1];   // [4,8,64,64]
    const float* enc_w = (const float*)d_in[4];   // [128,257,3,3]
    const float* enc_b = (const float*)d_in[5];
    const float* gcn_w = (const float*)d_in[6];   // [128,256,3,3]
    const float* gcn_b = (const float*)d_in[7];
    const float* ro_w  = (const float*)d_in[8];   // [1,384,3,3]
    const float* ro_b  = (const float*)d_in[9];
    float* out = (float*)d_out;                   // [4,8,64,64]

    // workspace (ushort units; fp32 tail)
    ushort_t* WencF  = (ushort_t*)d_ws;           // 294912
    ushort_t* WgcnS  = WencF + 294912;            // 147456
    ushort_t* WgcnD  = WgcnS + 147456;            // 147456
    ushort_t* WroQ   = WgcnD + 147456;            // 2304
    ushort_t* WroS   = WroQ + 2304;               // 1152
    ushort_t* featsT = WroS + 1152;               // [4][8cc][4096][32]
    ushort_t* Sa     = featsT + 4194304;          // [32][4cc][4096][32]
    ushort_t* Sb     = Sa + 16777216;
    ushort_t* USum   = Sb + 16777216;             // [4][4cc][4096][32]
    ushort_t* U1p16  = USum + 2097152;            // [4kz][4img][4cc][4096][32]
    ushort_t* U2p16  = U1p16 + 8388608;           // [4kz][4img][4cc][4096][32]
    float*    YR     = (float*)(U2p16 + 8388608); // 4*4096 fp32

    dim3 blk(256);

    prep_all<<<3344, blk, 0, stream>>>(feats, enc_w, gcn_w, ro_w,
                                       featsT, WencF, WgcnS, WgcnD, WroQ, WroS);

    // encoder shared conv: 4 fp16 kz-partials (K=576 each), 512 blocks
    conv_k<2, false, false><<<dim3(32, 4, 4), blk, 0, stream>>>(
        featsT, WencF, U1p16, nullptr, nullptr, 8);
    // ro_shared (64 LDS-staged blocks, scheduled first) + enc per-object
    enc_obj_ro<<<1088, blk, 0, stream>>>(masks, enc_w, enc_b, U1p16,
                                         featsT, WroQ, Sa, USum, YR);

    // step 1: shared partials -> fused object conv (zero-tail 512 blocks)
    conv_k<1, false, false><<<dim3(32, 4, 4), blk, 0, stream>>>(
        USum, WgcnS, U2p16, nullptr, nullptr, 4);
    conv_obj<<<dim3(16, 32), blk, 0, stream>>>(Sa, WgcnD, Sb, U2p16, gcn_b);

    // step 2: shared conv sums the 8 objects during staging (deletes sum8)
    conv_k<1, false, true><<<dim3(32, 4, 4), blk, 0, stream>>>(
        Sb, WgcnS, U2p16, nullptr, nullptr, 4);
    conv_obj<<<dim3(16, 32), blk, 0, stream>>>(Sb, WgcnD, Sa, U2p16, gcn_b);

    // readout (final states in Sa)
    ro_obj<<<dim3(16, 32), blk, 0, stream>>>(Sa, WroS, ro_b, YR, out);
}

// Round 14
// 237.814 us; speedup vs baseline: 1.4722x; 1.4722x over previous
//
#include <hip/hip_runtime.h>
#include <math.h>

// B=4, O=8, C=256, HID=128, H=W=64, STEPS=2
// v14 = v12 (session best, 245.3us measured): 3-slot-W conv_k @~50us = 781TF
// = 86% of the ~900TF m97-structure HIP plateau; LDS-staged ro_shared+ro_obj.
// v13's conv_obj (acc[4][8]) reverted: compiler caps at 128 VGPR even under
// (256,2) and spills (WRITE 74MB, MfmaUtil 15) — 4-row geometry disproven 3x.
//   prep -> encconv(4 kz-partials) -> [ro_shared + enc_obj_sum] ->
//   shconv1 -> objconv1(FUSE) -> shconv2(SUMIN) -> objconv2(FUSE) -> ro_obj
// Activations fp16 chunked HWC: x[img][cc][px][ci32] (4KB DMA-able slabs).

typedef unsigned short ushort_t;
typedef _Float16 f16x8 __attribute__((ext_vector_type(8)));
typedef _Float16 f16x2 __attribute__((ext_vector_type(2)));
typedef float f32x4 __attribute__((ext_vector_type(4)));

#define GLDS(gsrc, ldst)                                                      \
    __builtin_amdgcn_global_load_lds(                                         \
        (const __attribute__((address_space(1))) unsigned int*)(gsrc),        \
        (__attribute__((address_space(3))) unsigned int*)(ldst), 16, 0, 0)

#define WAITVM0() asm volatile("s_waitcnt vmcnt(0)" ::: "memory")
#define WAITVM2() asm volatile("s_waitcnt vmcnt(2)" ::: "memory")
#define WAITLGKM0() asm volatile("s_waitcnt lgkmcnt(0)" ::: "memory")

__device__ __forceinline__ ushort_t f2h(float f) {
    _Float16 h = (_Float16)f;
    return *(ushort_t*)&h;
}
__device__ __forceinline__ float h2f(ushort_t u) {
    _Float16 h = *(_Float16*)&u;
    return (float)h;
}

// ---- merged prep: blocks <1024: feats CHW->chunked HWC; rest: weight packing
__global__ __launch_bounds__(256) void prep_all(
    const float* __restrict__ feats, const float* __restrict__ enc_w,
    const float* __restrict__ gcn_w, const float* __restrict__ ro_w,
    ushort_t* __restrict__ featsT, ushort_t* __restrict__ WencF,
    ushort_t* __restrict__ WgcnS, ushort_t* __restrict__ WgcnD,
    ushort_t* __restrict__ WroQ, ushort_t* __restrict__ WroS)
{
    __shared__ float tile[64][65];
    int bid = blockIdx.x, t = threadIdx.x;
    if (bid < 1024) {                 // feats transform: pt|ct|img
        int pt = bid & 63, ct = (bid >> 6) & 3, img = bid >> 8;
        int px_l = t & 63;
        const float* src = feats + ((size_t)img * 256 + ct * 64) * 4096 + pt * 64;
#pragma unroll
        for (int j = 0; j < 16; ++j) {
            int ci_l = (t >> 6) + j * 4;
            tile[px_l][ci_l] = src[(size_t)ci_l * 4096 + px_l];
        }
        __syncthreads();
        int px = t >> 2;
#pragma unroll
        for (int j = 0; j < 2; ++j) {
            int c8 = ((t & 3) + j * 4) * 8;
            uint4 v; ushort_t* pv = (ushort_t*)&v;
#pragma unroll
            for (int k = 0; k < 8; ++k) pv[k] = f2h(tile[px][c8 + k]);
            int cc = ct * 2 + (c8 >> 5);
            *(uint4*)(featsT + ((size_t)img * 8 + cc) * 131072 +
                      (size_t)(pt * 64 + px) * 32 + (c8 & 31)) = v;
        }
        return;
    }
    int i = (bid - 1024) * 256 + t;
    if (i < 294912) {                 // WencF[t][cc8][co128][ci32]
        int ci32 = i & 31, co = (i >> 5) & 127, tc = i >> 12;
        int tt = tc >> 3, cc = tc & 7, ci = cc * 32 + ci32;
        WencF[i] = f2h(enc_w[(co * 257 + ci) * 9 + tt]);
    } else if (i < 442368) {          // WgcnS[t][cc4][co128][ci32]
        int j = i - 294912;
        int ci32 = j & 31, co = (j >> 5) & 127, tc = j >> 12;
        int tt = tc >> 2, cc = tc & 3, ci = cc * 32 + ci32;
        WgcnS[j] = f2h(gcn_w[(co * 256 + 128 + ci) * 9 + tt]);
    } else if (i < 589824) {          // WgcnD = W1 - W2
        int j = i - 442368;
        int ci32 = j & 31, co = (j >> 5) & 127, tc = j >> 12;
        int tt = tc >> 2, cc = tc & 3, ci = cc * 32 + ci32;
        WgcnD[j] = f2h(gcn_w[(co * 256 + ci) * 9 + tt] -
                       gcn_w[(co * 256 + 128 + ci) * 9 + tt]);
    } else if (i < 592128) {          // WroQ[8cc][4q][9t][8k]
        int j = i - 589824;
        int k = j & 7, r = j >> 3;
        int tt = r % 9, cq = r / 9, q = cq & 3, cc = cq >> 2;
        WroQ[j] = f2h(ro_w[(cc * 32 + q * 8 + k) * 9 + tt]);
    } else if (i < 593280) {          // WroS[4cc][4q][9t][8k]
        int j = i - 592128;
        int k = j & 7, r = j >> 3;
        int tt = r % 9, cq = r / 9, q = cq & 3, cc = cq >> 2;
        WroS[j] = f2h(ro_w[(256 + cc * 32 + q * 8 + k) * 9 + tt]);
    }
}

// ---- conv v11 (proven). grid (32 rowpairs, nimg, kz). Block: 128co x 128px,
// 4 waves (cg,pg); wave 64co x 64px. Single halo act [4][66][32]; 3-slot W
// rotation (W[kc] in slot kc%3, staged kc-2, AFTER the entry barrier into the
// slot whose reads were consumed at tap kc-1). 1 barrier/steady tap; counted
// vmcnt(2); vmcnt(0) only at the final tap.
// Swizzle: LDS(col,s') = global(col, s'^g(col)), g=(col>>1)&3.
// FUSE:  epilogue = relu(raw + sum4(addp partials) + bias) (gcn object conv).
// SUMIN: act staging sums 8 objects (img = batch; object stride ncc_img*131072).
template<int NCCBLK, bool FUSE, bool SUMIN>
__global__ __launch_bounds__(256, 3) void conv_k(
    const ushort_t* __restrict__ x, const ushort_t* __restrict__ W,
    ushort_t* __restrict__ out,
    const ushort_t* __restrict__ addp, const float* __restrict__ bias,
    int ncc_img)
{
    __shared__ ushort_t raw[20736];           // 41472 B -> 3 blocks/CU
    ushort_t* xs = raw;                       // [4 rows][66 cols][32ci] single
    ushort_t* wlds = raw + 8448;              // 3 x [128 co][32ci]
    ushort_t* eb16 = raw;                     // epilogue overlay [64][136]

    const int rp = blockIdx.x, img = blockIdx.y, kz = blockIdx.z;
    const int row0 = rp * 2;
    const int cc0 = kz * NCCBLK;
    const int nchunk = 9 * NCCBLK;
    const int tid = threadIdx.x;
    const int w = tid >> 6, lane = tid & 63, lq = lane >> 4, lr = lane & 15;
    const int cg = w >> 1, pg = w & 1;

    const size_t objstride = (size_t)ncc_img * 131072;
    const ushort_t* xb = SUMIN ? x + (size_t)img * 8 * objstride
                               : x + (size_t)img * objstride;
    // A-read base with slot swizzle: co = cg*64+lr (+16 per frag, g-invariant)
    const int aoff0 = (cg * 64 + lr) * 32 + (lq ^ ((lr >> 1) & 3)) * 8;

    // zero halo columns (0 and 65) of the act buffer, once (all slots -> inv)
    if (tid < 32) {
        int r = tid >> 3, c = (tid >> 2) & 1, s = tid & 3;
        *(uint4*)(xs + r * 2112 + (c ? 65 : 0) * 32 + s * 8) =
            make_uint4(0, 0, 0, 0);
    }

    f32x4 acc[4][4];
#pragma unroll
    for (int a = 0; a < 4; ++a)
#pragma unroll
        for (int p = 0; p < 4; ++p) acc[a][p] = (f32x4){0.f, 0.f, 0.f, 0.f};

    const int gy = row0 - 1 + w;
    const bool row_ok = (unsigned)gy < 64u;
#define STAGE_ACT(cc_)                                                          \
    {                                                                           \
        ushort_t* dstrow = xs + w * 2112;                                       \
        if (row_ok) {                                                           \
            const ushort_t* src = xb + (size_t)(cc_) * 131072 + (size_t)gy * 2048; \
            if constexpr (SUMIN) {                                              \
                _Pragma("unroll")                                               \
                for (int u_ = 0; u_ < 4; ++u_) {                                \
                    f16x8 a_ = {0, 0, 0, 0, 0, 0, 0, 0};                        \
                    _Pragma("unroll")                                           \
                    for (int o_ = 0; o_ < 8; ++o_)                              \
                        a_ = a_ + *(const f16x8*)(src + (size_t)o_ * objstride + \
                                                  u_ * 512 + lane * 8);         \
                    int colp_ = 1 + u_ * 16 + (lane >> 2);                      \
                    int ssw_ = (lane & 3) ^ ((colp_ >> 1) & 3);                 \
                    *(f16x8*)(dstrow + colp_ * 32 + ssw_ * 8) = a_;             \
                }                                                               \
            } else {                                                            \
                _Pragma("unroll")                                               \
                for (int u_ = 0; u_ < 4; ++u_) {                                \
                    int colp_ = 1 + u_ * 16 + (lane >> 2);                      \
                    int ssw_ = (lane & 3) ^ ((colp_ >> 1) & 3);                 \
                    GLDS(src + (size_t)(colp_ - 1) * 32 + ssw_ * 8,             \
                         dstrow + 32 + u_ * 512);                               \
                }                                                               \
            }                                                                   \
        } else {                                                                \
            _Pragma("unroll")                                                   \
            for (int u_ = 0; u_ < 4; ++u_)                                      \
                *(uint4*)(dstrow + 32 + u_ * 512 + lane * 8) =                  \
                    make_uint4(0, 0, 0, 0);                                     \
        }                                                                       \
    }
#define STAGE_W(t_, cc_, slot_)                                                 \
    {                                                                           \
        const ushort_t* src = W + ((size_t)((t_) * ncc_img + (cc_)) * 4096);    \
        ushort_t* dst = wlds + (slot_) * 4096;                                  \
        _Pragma("unroll")                                                       \
        for (int j_ = 0; j_ < 2; ++j_) {                                        \
            int co_ = (w * 2 + j_) * 16 + (lane >> 2);                          \
            int ssw_ = (lane & 3) ^ ((co_ >> 1) & 3);                           \
            GLDS(src + co_ * 32 + ssw_ * 8, dst + (w * 2 + j_) * 512);          \
        }                                                                       \
    }

    STAGE_ACT(cc0);
    STAGE_W(0, cc0, 0);
    STAGE_W(1, cc0, 1);
    WAITLGKM0();                 // publish halo zeros / SUMIN ds_writes

#pragma unroll
    for (int ccl = 0; ccl < NCCBLK; ++ccl) {
        const int cc = cc0 + ccl;
#pragma unroll
        for (int t = 0; t < 9; ++t) {
            const int kc = ccl * 9 + t;
            // entry: W[kc] (staged kc-2) landed; W[kc+1] stays in flight
            if (kc == nchunk - 1) { WAITVM0(); } else { WAITVM2(); }
            __builtin_amdgcn_s_barrier();

            if (t == 0 && ccl > 0) {
                // act[cc-1] reads were MFMA-consumed before the entry barrier
                STAGE_ACT(cc);
                if (kc + 2 < nchunk)
                    STAGE_W((kc + 2) % 9, cc0 + (kc + 2) / 9, (kc + 2) % 3);
                WAITVM2();       // act landed (leaves W[kc+2] in flight)
                WAITLGKM0();     // !row_ok zero ds_writes published
                __builtin_amdgcn_s_barrier();
            } else if (kc + 2 < nchunk) {
                // slot (kc+2)%3 held W[kc-1]: reads consumed at tap kc-1
                STAGE_W((kc + 2) % 9, cc0 + (kc + 2) / 9, (kc + 2) % 3);
            }

            const int dy = t / 3, dx = t - 3 * dy;
            const ushort_t* wl = wlds + (kc % 3) * 4096 + aoff0;
            const int colb = dx + lr;
            const int swb = lq ^ ((colb >> 1) & 3);
            const ushort_t* xl = xs + (pg + dy) * 2112 + colb * 32 + swb * 8;
            f16x8 A0 = *(const f16x8*)(wl);
            f16x8 A1 = *(const f16x8*)(wl + 512);
            f16x8 A2 = *(const f16x8*)(wl + 1024);
            f16x8 A3 = *(const f16x8*)(wl + 1536);
            f16x8 B0 = *(const f16x8*)(xl);
            f16x8 B1 = *(const f16x8*)(xl + 512);
            f16x8 B2 = *(const f16x8*)(xl + 1024);
            f16x8 B3 = *(const f16x8*)(xl + 1536);

            __builtin_amdgcn_s_setprio(1);
            acc[0][0] = __builtin_amdgcn_mfma_f32_16x16x32_f16(A0, B0, acc[0][0], 0, 0, 0);
            acc[1][0] = __builtin_amdgcn_mfma_f32_16x16x32_f16(A1, B0, acc[1][0], 0, 0, 0);
            acc[2][0] = __builtin_amdgcn_mfma_f32_16x16x32_f16(A2, B0, acc[2][0], 0, 0, 0);
            acc[3][0] = __builtin_amdgcn_mfma_f32_16x16x32_f16(A3, B0, acc[3][0], 0, 0, 0);
            acc[0][1] = __builtin_amdgcn_mfma_f32_16x16x32_f16(A0, B1, acc[0][1], 0, 0, 0);
            acc[1][1] = __builtin_amdgcn_mfma_f32_16x16x32_f16(A1, B1, acc[1][1], 0, 0, 0);
            acc[2][1] = __builtin_amdgcn_mfma_f32_16x16x32_f16(A2, B1, acc[2][1], 0, 0, 0);
            acc[3][1] = __builtin_amdgcn_mfma_f32_16x16x32_f16(A3, B1, acc[3][1], 0, 0, 0);
            acc[0][2] = __builtin_amdgcn_mfma_f32_16x16x32_f16(A0, B2, acc[0][2], 0, 0, 0);
            acc[1][2] = __builtin_amdgcn_mfma_f32_16x16x32_f16(A1, B2, acc[1][2], 0, 0, 0);
            acc[2][2] = __builtin_amdgcn_mfma_f32_16x16x32_f16(A2, B2, acc[2][2], 0, 0, 0);
            acc[3][2] = __builtin_amdgcn_mfma_f32_16x16x32_f16(A3, B2, acc[3][2], 0, 0, 0);
            acc[0][3] = __builtin_amdgcn_mfma_f32_16x16x32_f16(A0, B3, acc[0][3], 0, 0, 0);
            acc[1][3] = __builtin_amdgcn_mfma_f32_16x16x32_f16(A1, B3, acc[1][3], 0, 0, 0);
            acc[2][3] = __builtin_amdgcn_mfma_f32_16x16x32_f16(A2, B3, acc[2][3], 0, 0, 0);
            acc[3][3] = __builtin_amdgcn_mfma_f32_16x16x32_f16(A3, B3, acc[3][3], 0, 0, 0);
            __builtin_amdgcn_s_setprio(0);
        }
    }

    // ---- epilogue via LDS transpose, fp16 chunked out
    ushort_t* obase = out + (size_t)(kz * gridDim.y + img) * 524288;
    const int b4 = img >> 3;                  // batch (FUSE only)
#pragma unroll
    for (int r = 0; r < 2; ++r) {
        __syncthreads();
        if (pg == r) {
#pragma unroll
            for (int cf = 0; cf < 4; ++cf)
#pragma unroll
                for (int pf = 0; pf < 4; ++pf) {
                    int px = pf * 16 + lr;
                    int co_l = cg * 64 + cf * 16 + lq * 4;
                    ushort_t pk[4];
#pragma unroll
                    for (int j = 0; j < 4; ++j) pk[j] = f2h(acc[cf][pf][j]);
                    *(uint2*)(eb16 + px * 136 + co_l) = *(uint2*)pk;
                }
        }
        __syncthreads();
#pragma unroll
        for (int k2 = 0; k2 < 4; ++k2) {
            int i = tid + k2 * 256;
            int px = i >> 4, c16 = i & 15;
            int pxg = (row0 + r) * 64 + px;
            size_t coff = (size_t)(c16 >> 2) * 131072 + (size_t)pxg * 32 + (c16 & 3) * 8;
            uint4 v = *(uint4*)(eb16 + px * 136 + c16 * 8);
            if constexpr (FUSE) {
                const ushort_t* vp = (const ushort_t*)&v;
                float vv[8];
#pragma unroll
                for (int k = 0; k < 8; ++k) vv[k] = h2f(vp[k]) + bias[c16 * 8 + k];
#pragma unroll
                for (int p = 0; p < 4; ++p) {
                    uint4 av = *(const uint4*)(addp + (size_t)(p * 4 + b4) * 524288 + coff);
                    const ushort_t* ap = (const ushort_t*)&av;
#pragma unroll
                    for (int k = 0; k < 8; ++k) vv[k] += h2f(ap[k]);
                }
                uint4 sv; ushort_t* sp = (ushort_t*)&sv;
#pragma unroll
                for (int k = 0; k < 8; ++k) sp[k] = f2h(fmaxf(vv[k], 0.f));
                *(uint4*)(obase + coff) = sv;
            } else {
                *(uint4*)(obase + coff) = v;
            }
        }
    }
#undef STAGE_ACT
#undef STAGE_W
}

// ---- merged: bid<64: ro_shared v2 (LDS-staged, one block per (rq,b));
//              bid>=64: encoder per-object + object-sum (1024 blocks)
__global__ __launch_bounds__(256) void enc_obj_ro(
    const float* __restrict__ masks, const float* __restrict__ enc_w,
    const float* __restrict__ enc_b, const ushort_t* __restrict__ U1p,
    const ushort_t* __restrict__ featsT, const ushort_t* __restrict__ WroQ,
    ushort_t* __restrict__ S, ushort_t* __restrict__ USum,
    float* __restrict__ YR)
{
    __shared__ ushort_t sl[12288 + 2304];     // ro: [6][64][32] acts + WroQ
    ushort_t* wl = sl + 12288;
    int bid = blockIdx.x, tid = threadIdx.x;
    if (bid < 64) {
        // ---- ro_shared v2: bid = rq*4 + b; 4 output rows, 8 cc of featsT
        const int rq = bid >> 2, b = bid & 3;
        const int lane = tid & 63;
        const int yl = tid >> 6, x = tid & 63;
#pragma unroll
        for (int k = 0; k < 2; ++k) {         // WroQ: 2304 us = 288 uint4
            int idx = tid + k * 256;
            if (idx < 288)
                *(uint4*)(wl + idx * 8) = *(const uint4*)(WroQ + idx * 8);
        }
        float acc = 0.f;
#pragma unroll
        for (int cc = 0; cc < 8; ++cc) {
            __syncthreads();                  // prev-cc reads done (+W on cc=0)
            const ushort_t* fb = featsT + (size_t)(b * 8 + cc) * 131072;
#pragma unroll
            for (int k = 0; k < 6; ++k) {
                int c = (tid >> 6) * 6 + k;   // chunk 0..23
                int j = c >> 2, qd = c & 3;
                int gyr = rq * 4 - 1 + j;
                ushort_t* dst = sl + j * 2048 + qd * 512;   // wave-uniform
                if ((unsigned)gyr < 64u) {
                    int colq = qd * 16 + (lane >> 2);
                    GLDS(fb + (size_t)gyr * 2048 + colq * 32 +
                             ((lane & 3) ^ ((colq >> 1) & 3)) * 8,
                         dst);
                } else {
                    *(uint4*)(dst + lane * 8) = make_uint4(0, 0, 0, 0);
                }
            }
            __syncthreads();                  // drains vmcnt (GLDS) + lgkm
#pragma unroll
            for (int dy = 0; dy < 3; ++dy) {
                const ushort_t* rowp = sl + (yl + dy) * 2048;
#pragma unroll
                for (int dx = 0; dx < 3; ++dx) {
                    int gx = x + dx - 1;
                    if ((unsigned)gx >= 64u) continue;
                    const int tap = dy * 3 + dx;
#pragma unroll
                    for (int q = 0; q < 4; ++q) {
                        f16x8 sv = *(const f16x8*)(rowp + gx * 32 +
                                                   (q ^ ((gx >> 1) & 3)) * 8);
                        f16x8 wv = *(const f16x8*)(wl + ((cc * 4 + q) * 9 + tap) * 8);
                        f16x2 s0 = {sv[0], sv[1]}, s1 = {sv[2], sv[3]};
                        f16x2 s2 = {sv[4], sv[5]}, s3 = {sv[6], sv[7]};
                        f16x2 w0 = {wv[0], wv[1]}, w1 = {wv[2], wv[3]};
                        f16x2 w2 = {wv[4], wv[5]}, w3 = {wv[6], wv[7]};
                        acc = __builtin_amdgcn_fdot2(s0, w0, acc, false);
                        acc = __builtin_amdgcn_fdot2(s1, w1, acc, false);
                        acc = __builtin_amdgcn_fdot2(s2, w2, acc, false);
                        acc = __builtin_amdgcn_fdot2(s3, w3, acc, false);
                    }
                }
            }
        }
        YR[b * 4096 + (rq * 4 + yl) * 64 + x] = acc;
        return;
    }
    // ---- enc_obj_sum: i = b(2)|cc(2)|px(12)|s(2)
    int i = (bid - 64) * 256 + tid;
    int s = i & 3, px = (i >> 2) & 4095, cc = (i >> 14) & 3, b = i >> 16;
    int co = cc * 32 + s * 8;
    int y = px >> 6, xx = px & 63;
    size_t coff = (size_t)cc * 131072 + (size_t)px * 32 + s * 8;
    float base[8];
#pragma unroll
    for (int k = 0; k < 8; ++k) base[k] = enc_b[co + k];
#pragma unroll
    for (int p = 0; p < 4; ++p) {
        uint4 v = *(const uint4*)(U1p + (size_t)(p * 4 + b) * 524288 + coff);
        const ushort_t* vp = (const ushort_t*)&v;
#pragma unroll
        for (int k = 0; k < 8; ++k) base[k] += h2f(vp[k]);
    }
    float wm[8][9];
#pragma unroll
    for (int k = 0; k < 8; ++k) {
        const float* wp = enc_w + (size_t)((co + k) * 257 + 256) * 9;
#pragma unroll
        for (int t = 0; t < 9; ++t) wm[k][t] = wp[t];
    }
    float sacc[8] = {0, 0, 0, 0, 0, 0, 0, 0};
#pragma unroll
    for (int o = 0; o < 8; ++o) {
        const float* m = masks + (size_t)(b * 8 + o) * 4096;
        float mt[9];
#pragma unroll
        for (int dy = 0; dy < 3; ++dy)
#pragma unroll
            for (int dx = 0; dx < 3; ++dx) {
                int gy_ = y + dy - 1, gx = xx + dx - 1;
                mt[dy * 3 + dx] =
                    ((unsigned)gy_ < 64u && (unsigned)gx < 64u) ? m[gy_ * 64 + gx] : 0.f;
            }
        uint4 sv; ushort_t* sp = (ushort_t*)&sv;
#pragma unroll
        for (int k = 0; k < 8; ++k) {
            float acc = base[k];
#pragma unroll
            for (int t = 0; t < 9; ++t) acc = fmaf(mt[t], wm[k][t], acc);
            acc = fmaxf(acc, 0.f);
            sacc[k] += acc;
            sp[k] = f2h(acc);
        }
        *(uint4*)(S + (size_t)(b * 8 + o) * 524288 + coff) = sv;
    }
    uint4 sv; ushort_t* sp = (ushort_t*)&sv;
#pragma unroll
    for (int k = 0; k < 8; ++k) sp[k] = f2h(sacc[k]);
    *(uint4*)(USum + (size_t)b * 524288 + coff) = sv;
}

// ---- readout per-object v2: LDS-staged. grid (16 rowquads, 32 n).
__global__ __launch_bounds__(256) void ro_obj(
    const ushort_t* __restrict__ S, const ushort_t* __restrict__ WroS,
    const float* __restrict__ ro_b, const float* __restrict__ YR,
    float* __restrict__ out)
{
    __shared__ ushort_t sl[12288 + 1152];     // [6][64][32] acts + weights
    ushort_t* wl = sl + 12288;
    const int rq = blockIdx.x;                // 0..15 (4 rows each)
    const int n  = blockIdx.y;                // 0..31
    const int b  = n >> 3;
    const int tid = threadIdx.x;
    const int lane = tid & 63;
    const int yl = tid >> 6, x = tid & 63;    // output row-in-block, col

    if (tid < 144)                            // weights: 1152 us = 144 uint4
        *(uint4*)(wl + tid * 8) = *(const uint4*)(WroS + tid * 8);

    float acc = 0.f;
#pragma unroll
    for (int cc = 0; cc < 4; ++cc) {
        __syncthreads();                      // prev-cc reads done (+W on cc=0)
        const ushort_t* sb = S + ((size_t)n * 4 + cc) * 131072;
#pragma unroll
        for (int k = 0; k < 6; ++k) {
            int c = (tid >> 6) * 6 + k;       // chunk 0..23
            int j = c >> 2, qd = c & 3;
            int gyr = rq * 4 - 1 + j;
            ushort_t* dst = sl + j * 2048 + qd * 512;   // wave-uniform
            if ((unsigned)gyr < 64u) {
                int colq = qd * 16 + (lane >> 2);
                GLDS(sb + (size_t)gyr * 2048 + colq * 32 +
                         ((lane & 3) ^ ((colq >> 1) & 3)) * 8,
                     dst);
            } else {
                *(uint4*)(dst + lane * 8) = make_uint4(0, 0, 0, 0);
            }
        }
        __syncthreads();                      // drains vmcnt (GLDS) + lgkm
#pragma unroll
        for (int dy = 0; dy < 3; ++dy) {
            const ushort_t* rowp = sl + (yl + dy) * 2048;
#pragma unroll
            for (int dx = 0; dx < 3; ++dx) {
                int gx = x + dx - 1;
                if ((unsigned)gx >= 64u) continue;
                const int tap = dy * 3 + dx;
#pragma unroll
                for (int q = 0; q < 4; ++q) {
                    f16x8 sv = *(const f16x8*)(rowp + gx * 32 +
                                               (q ^ ((gx >> 1) & 3)) * 8);
                    f16x8 wv = *(const f16x8*)(wl + ((cc * 4 + q) * 9 + tap) * 8);
                    f16x2 s0 = {sv[0], sv[1]}, s1 = {sv[2], sv[3]};
                    f16x2 s2 = {sv[4], sv[5]}, s3 = {sv[6], sv[7]};
                    f16x2 w0 = {wv[0], wv[1]}, w1 = {wv[2], wv[3]};
                    f16x2 w2 = {wv[4], wv[5]}, w3 = {wv[6], wv[7]};
                    acc = __builtin_amdgcn_fdot2(s0, w0, acc, false);
                    acc = __builtin_amdgcn_fdot2(s1, w1, acc, false);
                    acc = __builtin_amdgcn_fdot2(s2, w2, acc, false);
                    acc = __builtin_amdgcn_fdot2(s3, w3, acc, false);
                }
            }
        }
    }
    int pxg = (rq * 4 + yl) * 64 + x;
    float v = acc + YR[b * 4096 + pxg] + ro_b[0];
    out[(size_t)n * 4096 + pxg] = 1.f / (1.f + __expf(-v));
}

extern "C" void kernel_launch(void* const* d_in, const int* in_sizes, int n_in,
                              void* d_out, int out_size, void* d_ws, size_t ws_size,
                              hipStream_t stream)
{
    const float* feats = (const float*)d_in[0];   // [4,256,64,64]
    const float* masks = (const float*)d_in[1];   // [4,8,64,64]
    const float* enc_w = (const float*)d_in[4];   // [128,257,3,3]
    const float* enc_b = (const float*)d_in[5];
    const float* gcn_w = (const float*)d_in[6];   // [128,256,3,3]
    const float* gcn_b = (const float*)d_in[7];
    const float* ro_w  = (const float*)d_in[8];   // [1,384,3,3]
    const float* ro_b  = (const float*)d_in[9];
    float* out = (float*)d_out;                   // [4,8,64,64]

    // workspace (ushort units; fp32 tail)
    ushort_t* WencF  = (ushort_t*)d_ws;           // 294912
    ushort_t* WgcnS  = WencF + 294912;            // 147456
    ushort_t* WgcnD  = WgcnS + 147456;            // 147456
    ushort_t* WroQ   = WgcnD + 147456;            // 2304
    ushort_t* WroS   = WroQ + 2304;               // 1152
    ushort_t* featsT = WroS + 1152;               // [4][8cc][4096][32]
    ushort_t* Sa     = featsT + 4194304;          // [32][4cc][4096][32]
    ushort_t* Sb     = Sa + 16777216;
    ushort_t* USum   = Sb + 16777216;             // [4][4cc][4096][32]
    ushort_t* U1p16  = USum + 2097152;            // [4kz][4img][4cc][4096][32]
    ushort_t* U2p16  = U1p16 + 8388608;           // [4kz][4img][4cc][4096][32]
    float*    YR     = (float*)(U2p16 + 8388608); // 4*4096 fp32

    dim3 blk(256);

    prep_all<<<3344, blk, 0, stream>>>(feats, enc_w, gcn_w, ro_w,
                                       featsT, WencF, WgcnS, WgcnD, WroQ, WroS);

    // encoder shared conv: 4 fp16 kz-partials (K=576 each), 512 blocks
    conv_k<2, false, false><<<dim3(32, 4, 4), blk, 0, stream>>>(
        featsT, WencF, U1p16, nullptr, nullptr, 8);
    // ro_shared (64 LDS-staged blocks, scheduled first) + enc per-object
    enc_obj_ro<<<1088, blk, 0, stream>>>(masks, enc_w, enc_b, U1p16,
                                         featsT, WroQ, Sa, USum, YR);

    // step 1: shared partials -> fused object conv
    conv_k<1, false, false><<<dim3(32, 4, 4), blk, 0, stream>>>(
        USum, WgcnS, U2p16, nullptr, nullptr, 4);
    conv_k<4, true, false><<<dim3(32, 32, 1), blk, 0, stream>>>(
        Sa, WgcnD, Sb, U2p16, gcn_b, 4);

    // step 2: shared conv sums the 8 objects during staging (deletes sum8)
    conv_k<1, false, true><<<dim3(32, 4, 4), blk, 0, stream>>>(
        Sb, WgcnS, U2p16, nullptr, nullptr, 4);
    conv_k<4, true, false><<<dim3(32, 32, 1), blk, 0, stream>>>(
        Sb, WgcnD, Sa, U2p16, gcn_b, 4);

    // readout (final states in Sa)
    ro_obj<<<dim3(16, 32), blk, 0, stream>>>(Sa, WroS, ro_b, YR, out);
}